// Round 6
// baseline (276.494 us; speedup 1.0000x reference)
//
#include <hip/hip_runtime.h>
#include <hip/hip_bf16.h>

// Problem constants: N=2, L=2048, S=2048, D=128, H=32
#define N_B 2
#define L_Q 2048
#define S_S 2048
#define D_D 128
#define H_H 32
// 1/sqrt(128) * log2(e), folded into K projection so attn uses exp2 directly
#define SCALEK (0.08838834764831845f * 1.4426950408889634f)

typedef __attribute__((ext_vector_type(8))) short bf8;   // 8 bf16 (4 VGPR)
typedef __attribute__((ext_vector_type(4))) short bf4;   // 4 bf16 (2 VGPR)
typedef __attribute__((ext_vector_type(4))) float f4;    // 4 f32

#define MFMA(a, b, c) __builtin_amdgcn_mfma_f32_16x16x32_bf16(a, b, c, 0, 0, 0)

__device__ __forceinline__ short f2bf(float x) {
    union { float f; unsigned u; } v; v.f = x;
    unsigned r = v.u + 0x7FFFu + ((v.u >> 16) & 1u);   // RNE
    return (short)(r >> 16);
}

// pack 4 f32 -> 4 bf16 (RNE) via v_cvt_pk_bf16_f32 (compiler-lowered)
__device__ __forceinline__ bf4 pk4(float a, float b, float c, float d) {
    union { __hip_bfloat162 h2[2]; bf4 v; } u;
    u.h2[0] = __float22bfloat162_rn(make_float2(a, b));
    u.h2[1] = __float22bfloat162_rn(make_float2(c, d));
    return u.v;
}

__device__ __forceinline__ bf8 cat44(bf4 lo, bf4 hi) {
    bf8 r;
    r[0] = lo[0]; r[1] = lo[1]; r[2] = lo[2]; r[3] = lo[3];
    r[4] = hi[0]; r[5] = hi[1]; r[6] = hi[2]; r[7] = hi[3];
    return r;
}

// 8 consecutive f32 from global -> bf16x8 fragment
__device__ __forceinline__ bf8 load8(const float* p) {
    const float4* q = (const float4*)p;
    float4 a = q[0], b = q[1];
    bf8 r;
    r[0] = f2bf(a.x); r[1] = f2bf(a.y); r[2] = f2bf(a.z); r[3] = f2bf(a.w);
    r[4] = f2bf(b.x); r[5] = f2bf(b.y); r[6] = f2bf(b.z); r[7] = f2bf(b.w);
    return r;
}

// async global->LDS, 16B per lane. lds dst must be wave-uniform base (+lane*16 implicit)
__device__ __forceinline__ void async16(const void* g, void* l) {
    __builtin_amdgcn_global_load_lds(
        (const __attribute__((address_space(1))) unsigned*)g,
        (__attribute__((address_space(3))) unsigned*)l, 16, 0, 0);
}

// ---------------- Kernel A: Wc [4096][128] f32 -> WcT [128][4096] bf16 ----------------
__global__ __launch_bounds__(256) void k_wct(const float* __restrict__ Wc,
                                             unsigned short* __restrict__ WcT) {
    int idx = blockIdx.x * 256 + threadIdx.x;   // 524288 total
    int n = idx >> 12;          // 0..127
    int k = idx & 4095;         // 0..4095
    WcT[idx] = (unsigned short)f2bf(Wc[k * D_D + n]);
}

// ---------------- Kernel A2: W[h][k][d] f32 -> WT[h][d][k] bf16 (Wk and Wv) ----------
// One block per (head, job). LDS tile [128][129] bf16 (pad 1 short: read phase lanes
// stride 8*129 shorts = bank step 4 -> 2-way max = free).
__global__ __launch_bounds__(256) void k_wt(const float* __restrict__ Wk,
        const float* __restrict__ Wv, unsigned short* __restrict__ WkT,
        unsigned short* __restrict__ WvT) {
    __shared__ unsigned short T[128][129];
    const int tid = threadIdx.x;
    const int h = blockIdx.x;
    const int job = blockIdx.y;
    const float* W = (job ? Wv : Wk) + (size_t)h * (D_D * D_D);
    unsigned short* WT = (job ? WvT : WkT) + (size_t)h * (D_D * D_D);

    // load coalesced [k][d], convert, store LDS [k][d]
    #pragma unroll
    for (int i = 0; i < 64; ++i) {
        int flat = i * 256 + tid;       // k*128 + d
        T[flat >> 7][flat & 127] = (unsigned short)f2bf(W[flat]);
    }
    __syncthreads();
    // write [d][k] coalesced: lane -> (d = idx>>4, k0 = (idx&15)*8)
    #pragma unroll
    for (int j8 = 0; j8 < 8; ++j8) {
        int idx = j8 * 256 + tid;
        int d = idx >> 4, k0 = (idx & 15) * 8;
        bf8 v;
        #pragma unroll
        for (int j = 0; j < 8; ++j) v[j] = (short)T[k0 + j][d];
        *(bf8*)(WT + d * D_D + k0) = v;
    }
}

// ---------------- Kernel B: K/V projections (LDS-free: W frags read from global) ----
// job 0: Kb[n][h][s][d]  = (states@Wk + bk) * SCALEK   (bf16, row-major in d)
// job 1: VTb[n][h][d][ps] = (states@Wv + bv)^T         (bf16, transposed, s PERMUTED:
//        within each 64-s chunk, s = g*32+b*16+lp*4+jj stored at p = g*32+lp*8+b*4+jj,
//        so one 16B read at byte g*64+lgrp*16 yields the 8 s-values of MFMA32 A-slots
//        k=lgrp*8+j, i.e. s = g*32 + (j>>2)*16 + lgrp*4 + (j&3).)
__global__ __launch_bounds__(256) void k_proj(const float* __restrict__ states,
        const unsigned short* __restrict__ WkT, const float* __restrict__ bk,
        const unsigned short* __restrict__ WvT, const float* __restrict__ bv,
        unsigned short* __restrict__ Kb, unsigned short* __restrict__ VTb) {
    const int tid = threadIdx.x;
    const int l = tid & 63, w = tid >> 6;
    const int lrow = l & 15, lgrp = l >> 4;
    const int bx = blockIdx.x;                  // (n*H + h)*32 + sc
    const int sc = bx & 31;
    const int nh = bx >> 5;
    const int h = nh & 31, n = nh >> 5;
    const int job = blockIdx.y;

    if (job == 0) {
        const unsigned short* WT = WkT + (size_t)h * (D_D * D_D);
        // M = 16 s-rows per wave, N = 128 d
        const float* srow = states + ((size_t)n * S_S + sc * 64 + w * 16 + lrow) * D_D;
        bf8 a[4];
        #pragma unroll
        for (int t = 0; t < 4; ++t) a[t] = load8(srow + t * 32 + lgrp * 8);
        f4 acc[8];
        #pragma unroll
        for (int i = 0; i < 8; ++i) acc[i] = (f4)(0.f);
        #pragma unroll
        for (int nf = 0; nf < 8; ++nf) {
            int drow = nf * 16 + lrow;          // B-frag n-index = d
            #pragma unroll
            for (int t = 0; t < 4; ++t) {
                bf8 b = *(const bf8*)(WT + drow * D_D + t * 32 + lgrp * 8);
                acc[nf] = MFMA(a[t], b, acc[nf]);
            }
        }
        unsigned short* Kout = Kb + (size_t)(n * H_H + h) * S_S * D_D;
        #pragma unroll
        for (int nf = 0; nf < 8; ++nf) {
            int dcol = nf * 16 + lrow;
            float bias = bk[h * D_D + dcol];
            #pragma unroll
            for (int r = 0; r < 4; ++r) {
                int srw = sc * 64 + w * 16 + lgrp * 4 + r;
                Kout[(size_t)srw * D_D + dcol] = (unsigned short)f2bf((acc[nf][r] + bias) * SCALEK);
            }
        }
    } else {
        const unsigned short* WT = WvT + (size_t)h * (D_D * D_D);
        // V^T: M = d (32 rows per wave), N = 64 s. A = Wv^T (global), B = states^T
        bf8 a[2][4];
        #pragma unroll
        for (int mf = 0; mf < 2; ++mf) {
            int drow = w * 32 + mf * 16 + lrow;
            #pragma unroll
            for (int t = 0; t < 4; ++t)
                a[mf][t] = *(const bf8*)(WT + drow * D_D + t * 32 + lgrp * 8);
        }
        f4 acc[2][4];
        #pragma unroll
        for (int mf = 0; mf < 2; ++mf)
            #pragma unroll
            for (int nf = 0; nf < 4; ++nf) acc[mf][nf] = (f4)(0.f);
        #pragma unroll
        for (int nf = 0; nf < 4; ++nf) {
            const float* srow = states + ((size_t)n * S_S + sc * 64 + nf * 16 + lrow) * D_D;
            #pragma unroll
            for (int t = 0; t < 4; ++t) {
                bf8 b = load8(srow + t * 32 + lgrp * 8);
                acc[0][nf] = MFMA(a[0][t], b, acc[0][nf]);
                acc[1][nf] = MFMA(a[1][t], b, acc[1][nf]);
            }
        }
        unsigned short* Vout = VTb + (size_t)(n * H_H + h) * D_D * S_S;
        #pragma unroll
        for (int mf = 0; mf < 2; ++mf) {
            #pragma unroll
            for (int r = 0; r < 4; ++r) {
                int drow = w * 32 + mf * 16 + lgrp * 4 + r;
                float bias = bv[h * D_D + drow];
                #pragma unroll
                for (int nf = 0; nf < 4; ++nf) {
                    // s_local = nf*16 + lrow  ->  permuted column within the 64-s chunk:
                    int p = ((nf >> 1) << 5) + ((lrow >> 2) << 3) + ((nf & 1) << 2) + (lrow & 3);
                    int scol = sc * 64 + p;
                    Vout[(size_t)drow * S_S + scol] = (unsigned short)f2bf(acc[mf][nf][r] + bias);
                }
            }
        }
    }
}

// ---------------- Kernel C: flash attention, fragment-chained, dbuf K/V ----------------
// block = 4 waves, q-tile 128 (32 rows/wave), s-chunks of 64.
// Swapped QK^T: sacc = mfma32(K-frag, Q-frag) -> S^T (lane holds P[s=16nf+4g+r][q=lrow]).
// D-frag chains as MFMA32 B-frag (two 16-s blocks concat to K=32). V^T s-PERMUTED so the
// matching A-operand is ONE conflict-free b128 read. __launch_bounds__(256,2): LDS caps
// us at 2 blocks/CU anyway -> give the compiler 256 VGPR so loop-invariant addresses
// hoist instead of rematerializing (R5: VALUBusy 51% from address math at 124 VGPR).
__global__ __launch_bounds__(256, 2) void k_attn(const float* __restrict__ query,
        const unsigned short* __restrict__ Kb, const unsigned short* __restrict__ VTb,
        unsigned short* __restrict__ CTX) {
    // LDS: Kbuf[2] @ 0/16384 ([64 s][256B] rows), Vbuf[2] @ 32768/49152 ([128 d][128B] rows)
    __shared__ char smem[65536];
    const int tid = threadIdx.x;
    const int l = tid & 63, w = tid >> 6;
    const int lrow = l & 15, lgrp = l >> 4;

    // XCD swizzle: 1024 blocks, 8 XCDs -> 128 consecutive work-ids per XCD
    const int bid = blockIdx.x;
    const int bx = (bid & 7) * 128 + (bid >> 3);
    const int qt = bx & 15;
    const int nh = bx >> 4;
    const int h = nh & 31, n = nh >> 5;
    const int qbase = qt * 128 + w * 32;

    // Q fragments as B-operand of swapped QK^T
    bf8 qf[2][4];
    #pragma unroll
    for (int mf = 0; mf < 2; ++mf) {
        const float* qp = query + ((size_t)n * L_Q + qbase + mf * 16 + lrow) * D_D;
        #pragma unroll
        for (int t = 0; t < 4; ++t) qf[mf][t] = load8(qp + t * 32 + lgrp * 8);
    }

    f4 oacc[2][8];   // O^T[d][q]: lane holds rows d = df*16 + 4*lgrp + r, col q = lrow
    #pragma unroll
    for (int mf = 0; mf < 2; ++mf)
        #pragma unroll
        for (int df = 0; df < 8; ++df) oacc[mf][df] = (f4)(0.f);
    float rsum[2] = {0.f, 0.f};   // per-lane: all values share q = lrow

    const char* Kg = (const char*)(Kb + (size_t)(n * H_H + h) * S_S * D_D);
    const char* Vg = (const char*)(VTb + (size_t)(n * H_H + h) * D_D * S_S);

    // stage s-chunk `sc2` into buffer `c` (pre-swizzled global source, linear LDS dst)
    auto stage = [&](int c, int sc2) {
        char* Kl = smem + c * 16384;
        char* Vl = smem + 32768 + c * 16384;
        #pragma unroll
        for (int rnd = 0; rnd < 4; ++rnd) {
            int o = w * 4096 + rnd * 1024 + l * 16;
            int r = o >> 8;
            int b = (o & 255) ^ ((r & 7) << 4);
            async16(Kg + (size_t)(sc2 * 64 + r) * 256 + b, Kl + w * 4096 + rnd * 1024);
        }
        #pragma unroll
        for (int rnd = 0; rnd < 4; ++rnd) {
            int o = w * 4096 + rnd * 1024 + l * 16;
            int r = o >> 7;
            int b = (o & 127) ^ ((r & 7) << 4);
            async16(Vg + (size_t)r * 4096 + sc2 * 128 + b, Vl + w * 4096 + rnd * 1024);
        }
    };

    // one s-iteration with STATIC buffer index (cur known at compile time per body)
    auto iter = [&](int cur, int sc2, bool prefetch) {
        if (prefetch) stage(cur ^ 1, sc2 + 1);
        const char* Klds = smem + cur * 16384;
        const char* Vlds = smem + 32768 + cur * 16384;

        // --- QK^T swapped ---
        f4 sacc[2][4];
        #pragma unroll
        for (int mf = 0; mf < 2; ++mf)
            #pragma unroll
            for (int nf = 0; nf < 4; ++nf) sacc[mf][nf] = (f4)(0.f);
        __builtin_amdgcn_s_setprio(1);
        #pragma unroll
        for (int nf = 0; nf < 4; ++nf) {
            int srow = nf * 16 + lrow;          // A-frag row = s
            int swz = (srow & 7) << 4;
            #pragma unroll
            for (int t = 0; t < 4; ++t) {
                bf8 kb = *(const bf8*)(Klds + srow * 256 + (((t * 32 + lgrp * 8) * 2) ^ swz));
                sacc[0][nf] = MFMA(kb, qf[0][t], sacc[0][nf]);
                sacc[1][nf] = MFMA(kb, qf[1][t], sacc[1][nf]);
            }
        }
        __builtin_amdgcn_s_setprio(0);

        // --- softmax: exp2 + lane-local sum + pack into K=32 B-operands ---
        bf8 pf[2][2];
        #pragma unroll
        for (int mf = 0; mf < 2; ++mf) {
            #pragma unroll
            for (int g = 0; g < 2; ++g) {
                bf4 pblk[2];
                #pragma unroll
                for (int b2 = 0; b2 < 2; ++b2) {
                    int nf = g * 2 + b2;
                    float p0 = __builtin_amdgcn_exp2f(sacc[mf][nf][0]);
                    float p1 = __builtin_amdgcn_exp2f(sacc[mf][nf][1]);
                    float p2 = __builtin_amdgcn_exp2f(sacc[mf][nf][2]);
                    float p3 = __builtin_amdgcn_exp2f(sacc[mf][nf][3]);
                    rsum[mf] += (p0 + p1) + (p2 + p3);
                    pblk[b2] = pk4(p0, p1, p2, p3);
                }
                pf[mf][g] = cat44(pblk[0], pblk[1]);
            }
        }

        // --- PV swapped, K=32 ---
        __builtin_amdgcn_s_setprio(1);
        #pragma unroll
        for (int df = 0; df < 8; ++df) {
            int drow = df * 16 + lrow;          // A-frag row = d
            int swz = (drow & 7) << 4;
            #pragma unroll
            for (int g = 0; g < 2; ++g) {
                bf8 vf = *(const bf8*)(Vlds + drow * 128 + ((g * 64 + lgrp * 16) ^ swz));
                oacc[0][df] = MFMA(vf, pf[0][g], oacc[0][df]);
                oacc[1][df] = MFMA(vf, pf[1][g], oacc[1][df]);
            }
        }
        __builtin_amdgcn_s_setprio(0);
        __syncthreads();    // implicit vmcnt(0): this iter's prefetch landed; LDS reuse safe
    };

    stage(0, 0);
    __syncthreads();          // chunk 0 landed
    for (int s2 = 0; s2 < 32; s2 += 2) {
        iter(0, s2, true);                 // even sc2 <= 30: always prefetch
        iter(1, s2 + 1, s2 + 1 < 31);      // odd sc2: prefetch unless 31
    }

    // reduce rsum over the 4 lane-groups (s-partitions); q = lrow stays lane-local
    float rinv[2];
    #pragma unroll
    for (int mf = 0; mf < 2; ++mf) {
        float v = rsum[mf];
        v += __shfl_xor(v, 16, 64);
        v += __shfl_xor(v, 32, 64);
        rinv[mf] = 1.f / v;
    }
    // store: lane holds 4 CONSECUTIVE d per (mf, df) -> packed 8B stores
    #pragma unroll
    for (int mf = 0; mf < 2; ++mf) {
        int qrow = qbase + mf * 16 + lrow;
        unsigned short* crow = CTX + (size_t)(n * L_Q + qrow) * 4096 + h * D_D;
        #pragma unroll
        for (int df = 0; df < 8; ++df) {
            bf4 o = pk4(oacc[mf][df][0] * rinv[mf], oacc[mf][df][1] * rinv[mf],
                        oacc[mf][df][2] * rinv[mf], oacc[mf][df][3] * rinv[mf]);
            *(bf4*)(crow + df * 16 + lgrp * 4) = o;
        }
    }
}

// ---------------- Kernel E: out = CTX @ Wc + bc (dbuf A staging) ----------------
__global__ __launch_bounds__(256) void k_out(const unsigned short* __restrict__ CTX,
        const unsigned short* __restrict__ WcT, const float* __restrict__ bc,
        float* __restrict__ out) {
    __shared__ char Alds[8192];   // 2 x [16][256B] swizzled
    const int tid = threadIdx.x;
    const int l = tid & 63, w = tid >> 6;
    const int lrow = l & 15, lgrp = l >> 4;
    const int m0 = blockIdx.x * 16;
    const char* Ag = (const char*)(CTX + (size_t)m0 * 4096);

    auto stage = [&](int c, int kc) {
        int o = w * 1024 + l * 16;
        int r = o >> 8;
        int b = (o & 255) ^ ((r & 7) << 4);
        async16(Ag + (size_t)r * 8192 + kc * 256 + b, Alds + c * 4096 + w * 1024);
    };

    f4 acc[2];
    acc[0] = (f4)(0.f); acc[1] = (f4)(0.f);
    stage(0, 0);
    __syncthreads();
    int cur = 0;
    for (int kc = 0; kc < 32; ++kc) {
        if (kc < 31) stage(cur ^ 1, kc + 1);
        const char* Ac = Alds + cur * 4096;
        #pragma unroll
        for (int t = 0; t < 4; ++t) {
            int swz = (lrow & 7) << 4;
            bf8 a = *(const bf8*)(Ac + lrow * 256 + (((t * 32 + lgrp * 8) * 2) ^ swz));
            #pragma unroll
            for (int nf = 0; nf < 2; ++nf) {
                int nc = w * 32 + nf * 16 + lrow;
                bf8 b = *(const bf8*)(WcT + (size_t)nc * 4096 + kc * 128 + t * 32 + lgrp * 8);
                acc[nf] = MFMA(a, b, acc[nf]);
            }
        }
        __syncthreads();
        cur ^= 1;
    }
    #pragma unroll
    for (int nf = 0; nf < 2; ++nf) {
        int nc = w * 32 + nf * 16 + lrow;
        float bias = bc[nc];
        #pragma unroll
        for (int r = 0; r < 4; ++r)
            out[(size_t)(m0 + lgrp * 4 + r) * D_D + nc] = acc[nf][r] + bias;
    }
}

extern "C" void kernel_launch(void* const* d_in, const int* in_sizes, int n_in,
                              void* d_out, int out_size, void* d_ws, size_t ws_size,
                              hipStream_t stream) {
    const float* query  = (const float*)d_in[0];
    const float* states = (const float*)d_in[1];
    const float* Wk = (const float*)d_in[2];
    const float* bk = (const float*)d_in[3];
    const float* Wv = (const float*)d_in[4];
    const float* bv = (const float*)d_in[5];
    const float* Wc = (const float*)d_in[6];
    const float* bc = (const float*)d_in[7];
    float* out = (float*)d_out;

    // workspace (bf16): Kb 32MB | VTb 32MB | CTX 32MB | WcT 1MB.
    // WkT/WvT (1MB each) OVERLAP the CTX region: they are consumed by k_proj,
    // and CTX is first written by k_attn (which runs after) -> no extra ws.
    char* ws = (char*)d_ws;
    unsigned short* Kb  = (unsigned short*)(ws);
    unsigned short* VTb = (unsigned short*)(ws + 33554432);
    unsigned short* CTX = (unsigned short*)(ws + 67108864);
    unsigned short* WkT = (unsigned short*)(ws + 67108864);
    unsigned short* WvT = (unsigned short*)(ws + 67108864 + 1048576);
    unsigned short* WcT = (unsigned short*)(ws + 100663296);

    k_wct<<<2048, 256, 0, stream>>>(Wc, WcT);
    dim3 gw(32, 2);
    k_wt<<<gw, 256, 0, stream>>>(Wk, Wv, WkT, WvT);
    dim3 gb(2048, 2);
    k_proj<<<gb, 256, 0, stream>>>(states, WkT, bk, WvT, bv, Kb, VTb);
    k_attn<<<1024, 256, 0, stream>>>(query, Kb, VTb, CTX);
    k_out<<<256, 256, 0, stream>>>(CTX, WcT, bc, out);
}

// Round 7
// 226.865 us; speedup vs baseline: 1.2188x; 1.2188x over previous
//
#include <hip/hip_runtime.h>
#include <hip/hip_bf16.h>

// Problem constants: N=2, L=2048, S=2048, D=128, H=32
#define N_B 2
#define L_Q 2048
#define S_S 2048
#define D_D 128
#define H_H 32
// 1/sqrt(128) * log2(e), folded into K projection so attn uses exp2 directly
#define SCALEK (0.08838834764831845f * 1.4426950408889634f)

typedef __attribute__((ext_vector_type(8))) short bf8;   // 8 bf16 (4 VGPR)
typedef __attribute__((ext_vector_type(4))) short bf4;   // 4 bf16 (2 VGPR)
typedef __attribute__((ext_vector_type(4))) float f4;    // 4 f32

#define MFMA(a, b, c) __builtin_amdgcn_mfma_f32_16x16x32_bf16(a, b, c, 0, 0, 0)

__device__ __forceinline__ short f2bf(float x) {
    union { float f; unsigned u; } v; v.f = x;
    unsigned r = v.u + 0x7FFFu + ((v.u >> 16) & 1u);   // RNE
    return (short)(r >> 16);
}

// pack 4 f32 -> 4 bf16 (RNE) via v_cvt_pk_bf16_f32 (compiler-lowered)
__device__ __forceinline__ bf4 pk4(float a, float b, float c, float d) {
    union { __hip_bfloat162 h2[2]; bf4 v; } u;
    u.h2[0] = __float22bfloat162_rn(make_float2(a, b));
    u.h2[1] = __float22bfloat162_rn(make_float2(c, d));
    return u.v;
}

__device__ __forceinline__ bf8 cat44(bf4 lo, bf4 hi) {
    bf8 r;
    r[0] = lo[0]; r[1] = lo[1]; r[2] = lo[2]; r[3] = lo[3];
    r[4] = hi[0]; r[5] = hi[1]; r[6] = hi[2]; r[7] = hi[3];
    return r;
}

// 8 consecutive f32 from global -> bf16x8 fragment
__device__ __forceinline__ bf8 load8(const float* p) {
    const float4* q = (const float4*)p;
    float4 a = q[0], b = q[1];
    bf8 r;
    r[0] = f2bf(a.x); r[1] = f2bf(a.y); r[2] = f2bf(a.z); r[3] = f2bf(a.w);
    r[4] = f2bf(b.x); r[5] = f2bf(b.y); r[6] = f2bf(b.z); r[7] = f2bf(b.w);
    return r;
}

// async global->LDS, 16B per lane. lds dst must be wave-uniform base (+lane*16 implicit)
__device__ __forceinline__ void async16(const void* g, void* l) {
    __builtin_amdgcn_global_load_lds(
        (const __attribute__((address_space(1))) unsigned*)g,
        (__attribute__((address_space(3))) unsigned*)l, 16, 0, 0);
}

// ---------------- Kernel A: Wc [4096][128] f32 -> WcF fragment layout ----------------
// WcF frag f16 = ((kc*8 + nfA)*4 + t)*64 + l  holds Wc^T[n=nfA*16+(l&15)][k=kc*128+t*32+(l>>4)*8 ..+8]
// so k_out's B-read at (kc,nfA,t) is ONE coalesced 1KB wave load.
__global__ __launch_bounds__(256) void k_wct(const float* __restrict__ Wc,
                                             unsigned short* __restrict__ WcF) {
    int f16 = blockIdx.x * 256 + threadIdx.x;   // 65536 fragments
    int l = f16 & 63, t = (f16 >> 6) & 3, nfA = (f16 >> 8) & 7, kc = f16 >> 11;
    int lrow = l & 15, lgrp = l >> 4;
    int kbase = kc * 128 + t * 32 + lgrp * 8;
    int n = nfA * 16 + lrow;
    bf8 v;
    #pragma unroll
    for (int j = 0; j < 8; ++j) v[j] = f2bf(Wc[(size_t)(kbase + j) * D_D + n]);
    *(bf8*)(WcF + (size_t)f16 * 8) = v;
}

// ---------------- Kernel A2: W[h][k][d] f32 -> WF fragment layout (Wk and Wv) --------
// WF frag f16 = (df*4 + t)*64 + l  holds W^T[d=df*16+(l&15)][k=t*32+(l>>4)*8 ..+8].
// One block per (head, job); LDS tile [128][129] (pad -> ~2-way reads, free).
__global__ __launch_bounds__(256) void k_wt(const float* __restrict__ Wk,
        const float* __restrict__ Wv, unsigned short* __restrict__ WkF,
        unsigned short* __restrict__ WvF) {
    __shared__ unsigned short T[128][129];
    const int tid = threadIdx.x;
    const int h = blockIdx.x;
    const int job = blockIdx.y;
    const float* W = (job ? Wv : Wk) + (size_t)h * (D_D * D_D);
    unsigned short* WF = (job ? WvF : WkF) + (size_t)h * (D_D * D_D);

    #pragma unroll
    for (int i = 0; i < 64; ++i) {
        int flat = i * 256 + tid;       // k*128 + d
        T[flat >> 7][flat & 127] = (unsigned short)f2bf(W[flat]);
    }
    __syncthreads();
    #pragma unroll
    for (int j8 = 0; j8 < 8; ++j8) {
        int f16 = j8 * 256 + tid;
        int l = f16 & 63, t = (f16 >> 6) & 3, df = (f16 >> 8) & 7;
        int lrow = l & 15, lgrp = l >> 4;
        bf8 v;
        #pragma unroll
        for (int j = 0; j < 8; ++j) v[j] = (short)T[t * 32 + lgrp * 8 + j][df * 16 + lrow];
        *(bf8*)(WF + (size_t)f16 * 8) = v;
    }
}

// ---------------- Kernel B: K/V projections (coalesced fragment W reads) ------------
// job 0: Kb[n][h][s][d]  = (states@Wk + bk) * SCALEK   (bf16, row-major in d)
// job 1: VTb[n][h][d][ps] = (states@Wv + bv)^T         (bf16, transposed, s PERMUTED:
//        within each 64-s chunk, s = g*32+b*16+lp*4+jj stored at p = g*32+lp*8+b*4+jj)
__global__ __launch_bounds__(256) void k_proj(const float* __restrict__ states,
        const unsigned short* __restrict__ WkF, const float* __restrict__ bk,
        const unsigned short* __restrict__ WvF, const float* __restrict__ bv,
        unsigned short* __restrict__ Kb, unsigned short* __restrict__ VTb) {
    const int tid = threadIdx.x;
    const int l = tid & 63, w = tid >> 6;
    const int lrow = l & 15, lgrp = l >> 4;
    const int bx = blockIdx.x;                  // (n*H + h)*32 + sc
    const int sc = bx & 31;
    const int nh = bx >> 5;
    const int h = nh & 31, n = nh >> 5;
    const int job = blockIdx.y;

    if (job == 0) {
        const unsigned short* WF = WkF + (size_t)h * (D_D * D_D);
        // M = 16 s-rows per wave, N = 128 d
        const float* srow = states + ((size_t)n * S_S + sc * 64 + w * 16 + lrow) * D_D;
        bf8 a[4];
        #pragma unroll
        for (int t = 0; t < 4; ++t) a[t] = load8(srow + t * 32 + lgrp * 8);
        f4 acc[8];
        #pragma unroll
        for (int i = 0; i < 8; ++i) acc[i] = (f4)(0.f);
        #pragma unroll
        for (int nf = 0; nf < 8; ++nf) {
            #pragma unroll
            for (int t = 0; t < 4; ++t) {
                bf8 b = *(const bf8*)(WF + (((nf * 4 + t) * 64 + l) << 3));
                acc[nf] = MFMA(a[t], b, acc[nf]);
            }
        }
        unsigned short* Kout = Kb + (size_t)(n * H_H + h) * S_S * D_D;
        #pragma unroll
        for (int nf = 0; nf < 8; ++nf) {
            int dcol = nf * 16 + lrow;
            float bias = bk[h * D_D + dcol];
            #pragma unroll
            for (int r = 0; r < 4; ++r) {
                int srw = sc * 64 + w * 16 + lgrp * 4 + r;
                Kout[(size_t)srw * D_D + dcol] = (unsigned short)f2bf((acc[nf][r] + bias) * SCALEK);
            }
        }
    } else {
        const unsigned short* WF = WvF + (size_t)h * (D_D * D_D);
        // V^T: M = d (32 rows per wave), N = 64 s. A = Wv^T frags (coalesced global)
        bf8 a[2][4];
        #pragma unroll
        for (int mf = 0; mf < 2; ++mf) {
            #pragma unroll
            for (int t = 0; t < 4; ++t)
                a[mf][t] = *(const bf8*)(WF + ((((w * 2 + mf) * 4 + t) * 64 + l) << 3));
        }
        f4 acc[2][4];
        #pragma unroll
        for (int mf = 0; mf < 2; ++mf)
            #pragma unroll
            for (int nf = 0; nf < 4; ++nf) acc[mf][nf] = (f4)(0.f);
        #pragma unroll
        for (int nf = 0; nf < 4; ++nf) {
            const float* srow = states + ((size_t)n * S_S + sc * 64 + nf * 16 + lrow) * D_D;
            #pragma unroll
            for (int t = 0; t < 4; ++t) {
                bf8 b = load8(srow + t * 32 + lgrp * 8);
                acc[0][nf] = MFMA(a[0][t], b, acc[0][nf]);
                acc[1][nf] = MFMA(a[1][t], b, acc[1][nf]);
            }
        }
        unsigned short* Vout = VTb + (size_t)(n * H_H + h) * D_D * S_S;
        #pragma unroll
        for (int mf = 0; mf < 2; ++mf) {
            #pragma unroll
            for (int r = 0; r < 4; ++r) {
                int drow = w * 32 + mf * 16 + lgrp * 4 + r;
                float bias = bv[h * D_D + drow];
                #pragma unroll
                for (int nf = 0; nf < 4; ++nf) {
                    int p = ((nf >> 1) << 5) + ((lrow >> 2) << 3) + ((nf & 1) << 2) + (lrow & 3);
                    int scol = sc * 64 + p;
                    Vout[(size_t)drow * S_S + scol] = (unsigned short)f2bf(acc[mf][nf][r] + bias);
                }
            }
        }
    }
}

// ---------------- Kernel C: flash attention, 8-wave blocks, fragment-chained --------
// block = 8 waves (512 thr), q-tile 256 (32 rows/wave), s-chunks of 64, dbuf K/V.
// 512 blocks = EXACTLY 2/CU -> 16 waves/CU; K/V chunk shared by 8 waves (halves
// stage traffic vs R6) and doubles latency-hiding occupancy.
__global__ __launch_bounds__(512) void k_attn(const float* __restrict__ query,
        const unsigned short* __restrict__ Kb, const unsigned short* __restrict__ VTb,
        unsigned short* __restrict__ CTX) {
    // LDS: Kbuf[2] @ 0/16384 ([64 s][256B]), Vbuf[2] @ 32768/49152 ([128 d][128B])
    __shared__ char smem[65536];
    const int tid = threadIdx.x;
    const int l = tid & 63, w = tid >> 6;          // w = 0..7
    const int lrow = l & 15, lgrp = l >> 4;

    // XCD swizzle: 512 blocks, 8 XCDs -> 64 consecutive work-ids per XCD (8 heads/XCD)
    const int bid = blockIdx.x;
    const int bx = (bid & 7) * 64 + (bid >> 3);
    const int qt = bx & 7;
    const int nh = bx >> 3;
    const int h = nh & 31, n = nh >> 5;
    const int qbase = qt * 256 + w * 32;

    // Q fragments as B-operand of swapped QK^T
    bf8 qf[2][4];
    #pragma unroll
    for (int mf = 0; mf < 2; ++mf) {
        const float* qp = query + ((size_t)n * L_Q + qbase + mf * 16 + lrow) * D_D;
        #pragma unroll
        for (int t = 0; t < 4; ++t) qf[mf][t] = load8(qp + t * 32 + lgrp * 8);
    }

    f4 oacc[2][8];   // O^T[d][q]: lane holds rows d = df*16 + 4*lgrp + r, col q = lrow
    #pragma unroll
    for (int mf = 0; mf < 2; ++mf)
        #pragma unroll
        for (int df = 0; df < 8; ++df) oacc[mf][df] = (f4)(0.f);
    float rsum[2] = {0.f, 0.f};

    const char* Kg = (const char*)(Kb + (size_t)(n * H_H + h) * S_S * D_D);
    const char* Vg = (const char*)(VTb + (size_t)(n * H_H + h) * D_D * S_S);

    // stage s-chunk: 32 wave-ops split over 8 waves (2 K + 2 V each)
    auto stage = [&](int c, int sc2) {
        char* Kl = smem + c * 16384;
        char* Vl = smem + 32768 + c * 16384;
        #pragma unroll
        for (int i = 0; i < 2; ++i) {
            int kop = w * 2 + i;
            int o = kop * 1024 + l * 16;
            int r = o >> 8;
            int b = (o & 255) ^ ((r & 7) << 4);
            async16(Kg + (size_t)(sc2 * 64 + r) * 256 + b, Kl + kop * 1024);
        }
        #pragma unroll
        for (int i = 0; i < 2; ++i) {
            int vop = w * 2 + i;
            int o = vop * 1024 + l * 16;
            int r = o >> 7;
            int b = (o & 127) ^ ((r & 7) << 4);
            async16(Vg + (size_t)r * 4096 + sc2 * 128 + b, Vl + vop * 1024);
        }
    };

    // one s-iteration with STATIC buffer index
    auto iter = [&](int cur, int sc2, bool prefetch) {
        if (prefetch) stage(cur ^ 1, sc2 + 1);
        const char* Klds = smem + cur * 16384;
        const char* Vlds = smem + 32768 + cur * 16384;

        // --- QK^T swapped ---
        f4 sacc[2][4];
        #pragma unroll
        for (int mf = 0; mf < 2; ++mf)
            #pragma unroll
            for (int nf = 0; nf < 4; ++nf) sacc[mf][nf] = (f4)(0.f);
        __builtin_amdgcn_s_setprio(1);
        #pragma unroll
        for (int nf = 0; nf < 4; ++nf) {
            int srow = nf * 16 + lrow;
            int swz = (srow & 7) << 4;
            #pragma unroll
            for (int t = 0; t < 4; ++t) {
                bf8 kb = *(const bf8*)(Klds + srow * 256 + (((t * 32 + lgrp * 8) * 2) ^ swz));
                sacc[0][nf] = MFMA(kb, qf[0][t], sacc[0][nf]);
                sacc[1][nf] = MFMA(kb, qf[1][t], sacc[1][nf]);
            }
        }
        __builtin_amdgcn_s_setprio(0);

        // --- softmax: exp2 + lane-local sum + pack into K=32 B-operands ---
        bf8 pf[2][2];
        #pragma unroll
        for (int mf = 0; mf < 2; ++mf) {
            #pragma unroll
            for (int g = 0; g < 2; ++g) {
                bf4 pblk[2];
                #pragma unroll
                for (int b2 = 0; b2 < 2; ++b2) {
                    int nf = g * 2 + b2;
                    float p0 = __builtin_amdgcn_exp2f(sacc[mf][nf][0]);
                    float p1 = __builtin_amdgcn_exp2f(sacc[mf][nf][1]);
                    float p2 = __builtin_amdgcn_exp2f(sacc[mf][nf][2]);
                    float p3 = __builtin_amdgcn_exp2f(sacc[mf][nf][3]);
                    rsum[mf] += (p0 + p1) + (p2 + p3);
                    pblk[b2] = pk4(p0, p1, p2, p3);
                }
                pf[mf][g] = cat44(pblk[0], pblk[1]);
            }
        }

        // --- PV swapped, K=32: V^T s-permuted -> ONE conflict-free b128 per frag ---
        __builtin_amdgcn_s_setprio(1);
        #pragma unroll
        for (int df = 0; df < 8; ++df) {
            int drow = df * 16 + lrow;
            int swz = (drow & 7) << 4;
            #pragma unroll
            for (int g = 0; g < 2; ++g) {
                bf8 vf = *(const bf8*)(Vlds + drow * 128 + ((g * 64 + lgrp * 16) ^ swz));
                oacc[0][df] = MFMA(vf, pf[0][g], oacc[0][df]);
                oacc[1][df] = MFMA(vf, pf[1][g], oacc[1][df]);
            }
        }
        __builtin_amdgcn_s_setprio(0);
        __syncthreads();    // implicit vmcnt(0): this iter's prefetch landed; LDS reuse safe
    };

    stage(0, 0);
    __syncthreads();
    for (int s2 = 0; s2 < 32; s2 += 2) {
        iter(0, s2, true);
        iter(1, s2 + 1, s2 + 1 < 31);
    }

    // reduce rsum over the 4 lane-groups; q = lrow stays lane-local
    float rinv[2];
    #pragma unroll
    for (int mf = 0; mf < 2; ++mf) {
        float v = rsum[mf];
        v += __shfl_xor(v, 16, 64);
        v += __shfl_xor(v, 32, 64);
        rinv[mf] = 1.f / v;
    }
    #pragma unroll
    for (int mf = 0; mf < 2; ++mf) {
        int qrow = qbase + mf * 16 + lrow;
        unsigned short* crow = CTX + (size_t)(n * L_Q + qrow) * 4096 + h * D_D;
        #pragma unroll
        for (int df = 0; df < 8; ++df) {
            bf4 o = pk4(oacc[mf][df][0] * rinv[mf], oacc[mf][df][1] * rinv[mf],
                        oacc[mf][df][2] * rinv[mf], oacc[mf][df][3] * rinv[mf]);
            *(bf4*)(crow + df * 16 + lgrp * 4) = o;
        }
    }
}

// ---------------- Kernel E: out = CTX @ Wc + bc (M=32/block, coalesced WcF) ---------
__global__ __launch_bounds__(256) void k_out(const unsigned short* __restrict__ CTX,
        const unsigned short* __restrict__ WcF, const float* __restrict__ bc,
        float* __restrict__ out) {
    __shared__ char Alds[16384];   // 2 x [32][256B] swizzled
    const int tid = threadIdx.x;
    const int l = tid & 63, w = tid >> 6;
    const int lrow = l & 15, lgrp = l >> 4;
    const int m0 = blockIdx.x * 32;      // 128 blocks
    const char* Ag = (const char*)(CTX + (size_t)m0 * 4096);

    auto stage = [&](int c, int kc) {
        #pragma unroll
        for (int i = 0; i < 2; ++i) {
            int o = (w * 2 + i) * 1024 + l * 16;
            int r = o >> 8;
            int b = (o & 255) ^ ((r & 7) << 4);
            async16(Ag + (size_t)r * 8192 + kc * 256 + b, Alds + c * 8192 + (w * 2 + i) * 1024);
        }
    };

    f4 acc[2][2];
    #pragma unroll
    for (int mi = 0; mi < 2; ++mi) { acc[mi][0] = (f4)(0.f); acc[mi][1] = (f4)(0.f); }
    stage(0, 0);
    __syncthreads();
    int cur = 0;
    for (int kc = 0; kc < 32; ++kc) {
        if (kc < 31) stage(cur ^ 1, kc + 1);
        const char* Ac = Alds + cur * 8192;
        #pragma unroll
        for (int t = 0; t < 4; ++t) {
            int swz = (lrow & 7) << 4;
            int co = ((t * 32 + lgrp * 8) * 2) ^ swz;
            bf8 a0 = *(const bf8*)(Ac + lrow * 256 + co);
            bf8 a1 = *(const bf8*)(Ac + (16 + lrow) * 256 + co);
            #pragma unroll
            for (int nf = 0; nf < 2; ++nf) {
                int nfA = w * 2 + nf;
                bf8 b = *(const bf8*)(WcF + ((size_t)(((kc * 8 + nfA) * 4 + t) * 64 + l) << 3));
                acc[0][nf] = MFMA(a0, b, acc[0][nf]);
                acc[1][nf] = MFMA(a1, b, acc[1][nf]);
            }
        }
        __syncthreads();
        cur ^= 1;
    }
    #pragma unroll
    for (int mi = 0; mi < 2; ++mi) {
        #pragma unroll
        for (int nf = 0; nf < 2; ++nf) {
            int nc = w * 32 + nf * 16 + lrow;
            float bias = bc[nc];
            #pragma unroll
            for (int r = 0; r < 4; ++r)
                out[(size_t)(m0 + mi * 16 + lgrp * 4 + r) * D_D + nc] = acc[mi][nf][r] + bias;
        }
    }
}

extern "C" void kernel_launch(void* const* d_in, const int* in_sizes, int n_in,
                              void* d_out, int out_size, void* d_ws, size_t ws_size,
                              hipStream_t stream) {
    const float* query  = (const float*)d_in[0];
    const float* states = (const float*)d_in[1];
    const float* Wk = (const float*)d_in[2];
    const float* bk = (const float*)d_in[3];
    const float* Wv = (const float*)d_in[4];
    const float* bv = (const float*)d_in[5];
    const float* Wc = (const float*)d_in[6];
    const float* bc = (const float*)d_in[7];
    float* out = (float*)d_out;

    // workspace (bf16): Kb 32MB | VTb 32MB | CTX 32MB | WcF 1MB.
    // WkF/WvF (1MB each) OVERLAP the CTX region: consumed by k_proj before
    // k_attn writes CTX -> no extra ws.
    char* ws = (char*)d_ws;
    unsigned short* Kb  = (unsigned short*)(ws);
    unsigned short* VTb = (unsigned short*)(ws + 33554432);
    unsigned short* CTX = (unsigned short*)(ws + 67108864);
    unsigned short* WkF = (unsigned short*)(ws + 67108864);
    unsigned short* WvF = (unsigned short*)(ws + 67108864 + 1048576);
    unsigned short* WcF = (unsigned short*)(ws + 100663296);

    k_wct<<<256, 256, 0, stream>>>(Wc, WcF);
    dim3 gw(32, 2);
    k_wt<<<gw, 256, 0, stream>>>(Wk, Wv, WkF, WvF);
    dim3 gb(2048, 2);
    k_proj<<<gb, 256, 0, stream>>>(states, WkF, bk, WvF, bv, Kb, VTb);
    k_attn<<<512, 512, 0, stream>>>(query, Kb, VTb, CTX);
    k_out<<<128, 256, 0, stream>>>(CTX, WcF, bc, out);
}

// Round 8
// 225.977 us; speedup vs baseline: 1.2235x; 1.0039x over previous
//
#include <hip/hip_runtime.h>
#include <hip/hip_bf16.h>

// Problem constants: N=2, L=2048, S=2048, D=128, H=32
#define N_B 2
#define L_Q 2048
#define S_S 2048
#define D_D 128
#define H_H 32
// 1/sqrt(128) * log2(e), folded into K projection so attn uses exp2 directly
#define SCALEK (0.08838834764831845f * 1.4426950408889634f)

typedef __attribute__((ext_vector_type(8))) short bf8;   // 8 bf16 (4 VGPR)
typedef __attribute__((ext_vector_type(4))) short bf4;   // 4 bf16 (2 VGPR)
typedef __attribute__((ext_vector_type(4))) float f4;    // 4 f32

#define MFMA(a, b, c) __builtin_amdgcn_mfma_f32_16x16x32_bf16(a, b, c, 0, 0, 0)

__device__ __forceinline__ short f2bf(float x) {
    union { float f; unsigned u; } v; v.f = x;
    unsigned r = v.u + 0x7FFFu + ((v.u >> 16) & 1u);   // RNE
    return (short)(r >> 16);
}

// pack 4 f32 -> 4 bf16 (RNE) via v_cvt_pk_bf16_f32 (compiler-lowered)
__device__ __forceinline__ bf4 pk4(float a, float b, float c, float d) {
    union { __hip_bfloat162 h2[2]; bf4 v; } u;
    u.h2[0] = __float22bfloat162_rn(make_float2(a, b));
    u.h2[1] = __float22bfloat162_rn(make_float2(c, d));
    return u.v;
}

__device__ __forceinline__ bf8 cat44(bf4 lo, bf4 hi) {
    bf8 r;
    r[0] = lo[0]; r[1] = lo[1]; r[2] = lo[2]; r[3] = lo[3];
    r[4] = hi[0]; r[5] = hi[1]; r[6] = hi[2]; r[7] = hi[3];
    return r;
}

// 8 consecutive f32 from global -> bf16x8 fragment
__device__ __forceinline__ bf8 load8(const float* p) {
    const float4* q = (const float4*)p;
    float4 a = q[0], b = q[1];
    bf8 r;
    r[0] = f2bf(a.x); r[1] = f2bf(a.y); r[2] = f2bf(a.z); r[3] = f2bf(a.w);
    r[4] = f2bf(b.x); r[5] = f2bf(b.y); r[6] = f2bf(b.z); r[7] = f2bf(b.w);
    return r;
}

// async global->LDS, 16B per lane. lds dst must be wave-uniform base (+lane*16 implicit)
__device__ __forceinline__ void async16(const void* g, void* l) {
    __builtin_amdgcn_global_load_lds(
        (const __attribute__((address_space(1))) unsigned*)g,
        (__attribute__((address_space(3))) unsigned*)l, 16, 0, 0);
}

// ---------------- Kernel A: Wc [4096][128] f32 -> WcF fragment layout ----------------
__global__ __launch_bounds__(256) void k_wct(const float* __restrict__ Wc,
                                             unsigned short* __restrict__ WcF) {
    int f16 = blockIdx.x * 256 + threadIdx.x;   // 65536 fragments
    int l = f16 & 63, t = (f16 >> 6) & 3, nfA = (f16 >> 8) & 7, kc = f16 >> 11;
    int lrow = l & 15, lgrp = l >> 4;
    int kbase = kc * 128 + t * 32 + lgrp * 8;
    int n = nfA * 16 + lrow;
    bf8 v;
    #pragma unroll
    for (int j = 0; j < 8; ++j) v[j] = f2bf(Wc[(size_t)(kbase + j) * D_D + n]);
    *(bf8*)(WcF + (size_t)f16 * 8) = v;
}

// ---------------- Kernel A2: W[h][k][d] f32 -> WF fragment layout (Wk and Wv) --------
__global__ __launch_bounds__(256) void k_wt(const float* __restrict__ Wk,
        const float* __restrict__ Wv, unsigned short* __restrict__ WkF,
        unsigned short* __restrict__ WvF) {
    __shared__ unsigned short T[128][129];
    const int tid = threadIdx.x;
    const int h = blockIdx.x;
    const int job = blockIdx.y;
    const float* W = (job ? Wv : Wk) + (size_t)h * (D_D * D_D);
    unsigned short* WF = (job ? WvF : WkF) + (size_t)h * (D_D * D_D);

    #pragma unroll
    for (int i = 0; i < 64; ++i) {
        int flat = i * 256 + tid;       // k*128 + d
        T[flat >> 7][flat & 127] = (unsigned short)f2bf(W[flat]);
    }
    __syncthreads();
    #pragma unroll
    for (int j8 = 0; j8 < 8; ++j8) {
        int f16 = j8 * 256 + tid;
        int l = f16 & 63, t = (f16 >> 6) & 3, df = (f16 >> 8) & 7;
        int lrow = l & 15, lgrp = l >> 4;
        bf8 v;
        #pragma unroll
        for (int j = 0; j < 8; ++j) v[j] = (short)T[t * 32 + lgrp * 8 + j][df * 16 + lrow];
        *(bf8*)(WF + (size_t)f16 * 8) = v;
    }
}

// ---------------- Kernel B: K/V projections (coalesced fragment W reads) ------------
__global__ __launch_bounds__(256) void k_proj(const float* __restrict__ states,
        const unsigned short* __restrict__ WkF, const float* __restrict__ bk,
        const unsigned short* __restrict__ WvF, const float* __restrict__ bv,
        unsigned short* __restrict__ Kb, unsigned short* __restrict__ VTb) {
    const int tid = threadIdx.x;
    const int l = tid & 63, w = tid >> 6;
    const int lrow = l & 15, lgrp = l >> 4;
    const int bx = blockIdx.x;                  // (n*H + h)*32 + sc
    const int sc = bx & 31;
    const int nh = bx >> 5;
    const int h = nh & 31, n = nh >> 5;
    const int job = blockIdx.y;

    if (job == 0) {
        const unsigned short* WF = WkF + (size_t)h * (D_D * D_D);
        const float* srow = states + ((size_t)n * S_S + sc * 64 + w * 16 + lrow) * D_D;
        bf8 a[4];
        #pragma unroll
        for (int t = 0; t < 4; ++t) a[t] = load8(srow + t * 32 + lgrp * 8);
        f4 acc[8];
        #pragma unroll
        for (int i = 0; i < 8; ++i) acc[i] = (f4)(0.f);
        #pragma unroll
        for (int nf = 0; nf < 8; ++nf) {
            #pragma unroll
            for (int t = 0; t < 4; ++t) {
                bf8 b = *(const bf8*)(WF + (((nf * 4 + t) * 64 + l) << 3));
                acc[nf] = MFMA(a[t], b, acc[nf]);
            }
        }
        unsigned short* Kout = Kb + (size_t)(n * H_H + h) * S_S * D_D;
        #pragma unroll
        for (int nf = 0; nf < 8; ++nf) {
            int dcol = nf * 16 + lrow;
            float bias = bk[h * D_D + dcol];
            #pragma unroll
            for (int r = 0; r < 4; ++r) {
                int srw = sc * 64 + w * 16 + lgrp * 4 + r;
                Kout[(size_t)srw * D_D + dcol] = (unsigned short)f2bf((acc[nf][r] + bias) * SCALEK);
            }
        }
    } else {
        const unsigned short* WF = WvF + (size_t)h * (D_D * D_D);
        bf8 a[2][4];
        #pragma unroll
        for (int mf = 0; mf < 2; ++mf) {
            #pragma unroll
            for (int t = 0; t < 4; ++t)
                a[mf][t] = *(const bf8*)(WF + ((((w * 2 + mf) * 4 + t) * 64 + l) << 3));
        }
        f4 acc[2][4];
        #pragma unroll
        for (int mf = 0; mf < 2; ++mf)
            #pragma unroll
            for (int nf = 0; nf < 4; ++nf) acc[mf][nf] = (f4)(0.f);
        #pragma unroll
        for (int nf = 0; nf < 4; ++nf) {
            const float* srow = states + ((size_t)n * S_S + sc * 64 + nf * 16 + lrow) * D_D;
            #pragma unroll
            for (int t = 0; t < 4; ++t) {
                bf8 b = load8(srow + t * 32 + lgrp * 8);
                acc[0][nf] = MFMA(a[0][t], b, acc[0][nf]);
                acc[1][nf] = MFMA(a[1][t], b, acc[1][nf]);
            }
        }
        unsigned short* Vout = VTb + (size_t)(n * H_H + h) * D_D * S_S;
        #pragma unroll
        for (int mf = 0; mf < 2; ++mf) {
            #pragma unroll
            for (int r = 0; r < 4; ++r) {
                int drow = w * 32 + mf * 16 + lgrp * 4 + r;
                float bias = bv[h * D_D + drow];
                #pragma unroll
                for (int nf = 0; nf < 4; ++nf) {
                    int p = ((nf >> 1) << 5) + ((lrow >> 2) << 3) + ((nf & 1) << 2) + (lrow & 3);
                    int scol = sc * 64 + p;
                    Vout[(size_t)drow * S_S + scol] = (unsigned short)f2bf(acc[mf][nf][r] + bias);
                }
            }
        }
    }
}

// ---------------- Kernel C: flash attention, PV-deferred software pipeline ----------
// block = 8 waves (512 thr), q-tile 256 (32 rows/wave), s-chunks of 64, dbuf K/V.
// R7 post-mortem: phase lockstep -> zero pipe overlap (iter wall = LDS+VALU+MFMA sum).
// Fix: defer PV by ONE chunk. V-frags of chunk i-1 live in vreg[16]; PV(i-1) is pure
// register MFMA at the top of iter i -> independent of iter i's LDS reads -> every
// wave always has both MFMA and LDS work in flight. Epilogue PV drains chunk 31.
__global__ __launch_bounds__(512, 2) void k_attn(const float* __restrict__ query,
        const unsigned short* __restrict__ Kb, const unsigned short* __restrict__ VTb,
        unsigned short* __restrict__ CTX) {
    // LDS: Kbuf[2] @ 0/16384 ([64 s][256B]), Vbuf[2] @ 32768/49152 ([128 d][128B])
    __shared__ char smem[65536];
    const int tid = threadIdx.x;
    const int l = tid & 63, w = tid >> 6;          // w = 0..7
    const int lrow = l & 15, lgrp = l >> 4;

    // XCD swizzle: 512 blocks, 8 XCDs -> 64 consecutive work-ids per XCD (8 heads/XCD)
    const int bid = blockIdx.x;
    const int bx = (bid & 7) * 64 + (bid >> 3);
    const int qt = bx & 7;
    const int nh = bx >> 3;
    const int h = nh & 31, n = nh >> 5;
    const int qbase = qt * 256 + w * 32;

    // Q fragments as B-operand of swapped QK^T
    bf8 qf[2][4];
    #pragma unroll
    for (int mf = 0; mf < 2; ++mf) {
        const float* qp = query + ((size_t)n * L_Q + qbase + mf * 16 + lrow) * D_D;
        #pragma unroll
        for (int t = 0; t < 4; ++t) qf[mf][t] = load8(qp + t * 32 + lgrp * 8);
    }

    f4 oacc[2][8];   // O^T[d][q]: lane holds rows d = df*16 + 4*lgrp + r, col q = lrow
    #pragma unroll
    for (int mf = 0; mf < 2; ++mf)
        #pragma unroll
        for (int df = 0; df < 8; ++df) oacc[mf][df] = (f4)(0.f);
    float rsum[2] = {0.f, 0.f};

    bf8 vreg[16];    // V-frags of PREVIOUS chunk: [df][g] -> vreg[df*2+g]
    bf8 pf[2][2];    // P-frags of PREVIOUS chunk (K=32 B-operands)

    const char* Kg = (const char*)(Kb + (size_t)(n * H_H + h) * S_S * D_D);
    const char* Vg = (const char*)(VTb + (size_t)(n * H_H + h) * D_D * S_S);

    // stage s-chunk: 32 wave-ops split over 8 waves (2 K + 2 V each)
    auto stage = [&](int c, int sc2) {
        char* Kl = smem + c * 16384;
        char* Vl = smem + 32768 + c * 16384;
        #pragma unroll
        for (int i = 0; i < 2; ++i) {
            int kop = w * 2 + i;
            int o = kop * 1024 + l * 16;
            int r = o >> 8;
            int b = (o & 255) ^ ((r & 7) << 4);
            async16(Kg + (size_t)(sc2 * 64 + r) * 256 + b, Kl + kop * 1024);
        }
        #pragma unroll
        for (int i = 0; i < 2; ++i) {
            int vop = w * 2 + i;
            int o = vop * 1024 + l * 16;
            int r = o >> 7;
            int b = (o & 127) ^ ((r & 7) << 4);
            async16(Vg + (size_t)r * 4096 + sc2 * 128 + b, Vl + vop * 1024);
        }
    };

    // PV of the PREVIOUS chunk: pure register MFMA (overlaps current chunk's LDS reads)
    auto pv = [&]() {
        __builtin_amdgcn_s_setprio(1);
        #pragma unroll
        for (int df = 0; df < 8; ++df) {
            #pragma unroll
            for (int g = 0; g < 2; ++g) {
                oacc[0][df] = MFMA(vreg[df * 2 + g], pf[0][g], oacc[0][df]);
                oacc[1][df] = MFMA(vreg[df * 2 + g], pf[1][g], oacc[1][df]);
            }
        }
        __builtin_amdgcn_s_setprio(0);
    };

    // one s-iteration with STATIC buffer index
    auto iter = [&](int cur, int sc2, bool dopv, bool prefetch) {
        if (prefetch) stage(cur ^ 1, sc2 + 1);
        if (dopv) pv();          // consumes vreg/pf of chunk sc2-1 (register-only)
        const char* Klds = smem + cur * 16384;
        const char* Vlds = smem + 32768 + cur * 16384;

        // refill vreg with THIS chunk's V-frags (after pv consumed the old values)
        #pragma unroll
        for (int df = 0; df < 8; ++df) {
            int drow = df * 16 + lrow;
            int swz = (drow & 7) << 4;
            #pragma unroll
            for (int g = 0; g < 2; ++g)
                vreg[df * 2 + g] = *(const bf8*)(Vlds + drow * 128 + ((g * 64 + lgrp * 16) ^ swz));
        }

        // QK^T swapped
        f4 sacc[2][4];
        #pragma unroll
        for (int mf = 0; mf < 2; ++mf)
            #pragma unroll
            for (int nf = 0; nf < 4; ++nf) sacc[mf][nf] = (f4)(0.f);
        __builtin_amdgcn_s_setprio(1);
        #pragma unroll
        for (int nf = 0; nf < 4; ++nf) {
            int srow = nf * 16 + lrow;
            int swz = (srow & 7) << 4;
            #pragma unroll
            for (int t = 0; t < 4; ++t) {
                bf8 kb = *(const bf8*)(Klds + srow * 256 + (((t * 32 + lgrp * 8) * 2) ^ swz));
                sacc[0][nf] = MFMA(kb, qf[0][t], sacc[0][nf]);
                sacc[1][nf] = MFMA(kb, qf[1][t], sacc[1][nf]);
            }
        }
        __builtin_amdgcn_s_setprio(0);

        // softmax: exp2 + lane-local sum + pack into K=32 B-operands -> pf (for NEXT iter)
        #pragma unroll
        for (int mf = 0; mf < 2; ++mf) {
            #pragma unroll
            for (int g = 0; g < 2; ++g) {
                bf4 pblk[2];
                #pragma unroll
                for (int b2 = 0; b2 < 2; ++b2) {
                    int nf = g * 2 + b2;
                    float p0 = __builtin_amdgcn_exp2f(sacc[mf][nf][0]);
                    float p1 = __builtin_amdgcn_exp2f(sacc[mf][nf][1]);
                    float p2 = __builtin_amdgcn_exp2f(sacc[mf][nf][2]);
                    float p3 = __builtin_amdgcn_exp2f(sacc[mf][nf][3]);
                    rsum[mf] += (p0 + p1) + (p2 + p3);
                    pblk[b2] = pk4(p0, p1, p2, p3);
                }
                pf[mf][g] = cat44(pblk[0], pblk[1]);
            }
        }
        __syncthreads();    // implicit vmcnt(0)+lgkmcnt(0): prefetch landed, reads done
    };

    stage(0, 0);
    __syncthreads();
    for (int s2 = 0; s2 < 32; s2 += 2) {
        iter(0, s2, s2 > 0, true);
        iter(1, s2 + 1, true, s2 + 1 < 31);
    }
    pv();   // drain chunk 31

    // reduce rsum over the 4 lane-groups; q = lrow stays lane-local
    float rinv[2];
    #pragma unroll
    for (int mf = 0; mf < 2; ++mf) {
        float v = rsum[mf];
        v += __shfl_xor(v, 16, 64);
        v += __shfl_xor(v, 32, 64);
        rinv[mf] = 1.f / v;
    }
    #pragma unroll
    for (int mf = 0; mf < 2; ++mf) {
        int qrow = qbase + mf * 16 + lrow;
        unsigned short* crow = CTX + (size_t)(n * L_Q + qrow) * 4096 + h * D_D;
        #pragma unroll
        for (int df = 0; df < 8; ++df) {
            bf4 o = pk4(oacc[mf][df][0] * rinv[mf], oacc[mf][df][1] * rinv[mf],
                        oacc[mf][df][2] * rinv[mf], oacc[mf][df][3] * rinv[mf]);
            *(bf4*)(crow + df * 16 + lgrp * 4) = o;
        }
    }
}

// ---------------- Kernel E: out = CTX @ Wc + bc (M=32/block, coalesced WcF) ---------
__global__ __launch_bounds__(256) void k_out(const unsigned short* __restrict__ CTX,
        const unsigned short* __restrict__ WcF, const float* __restrict__ bc,
        float* __restrict__ out) {
    __shared__ char Alds[16384];   // 2 x [32][256B] swizzled
    const int tid = threadIdx.x;
    const int l = tid & 63, w = tid >> 6;
    const int lrow = l & 15, lgrp = l >> 4;
    const int m0 = blockIdx.x * 32;      // 128 blocks
    const char* Ag = (const char*)(CTX + (size_t)m0 * 4096);

    auto stage = [&](int c, int kc) {
        #pragma unroll
        for (int i = 0; i < 2; ++i) {
            int o = (w * 2 + i) * 1024 + l * 16;
            int r = o >> 8;
            int b = (o & 255) ^ ((r & 7) << 4);
            async16(Ag + (size_t)r * 8192 + kc * 256 + b, Alds + c * 8192 + (w * 2 + i) * 1024);
        }
    };

    f4 acc[2][2];
    #pragma unroll
    for (int mi = 0; mi < 2; ++mi) { acc[mi][0] = (f4)(0.f); acc[mi][1] = (f4)(0.f); }
    stage(0, 0);
    __syncthreads();
    int cur = 0;
    for (int kc = 0; kc < 32; ++kc) {
        if (kc < 31) stage(cur ^ 1, kc + 1);
        const char* Ac = Alds + cur * 8192;
        #pragma unroll
        for (int t = 0; t < 4; ++t) {
            int swz = (lrow & 7) << 4;
            int co = ((t * 32 + lgrp * 8) * 2) ^ swz;
            bf8 a0 = *(const bf8*)(Ac + lrow * 256 + co);
            bf8 a1 = *(const bf8*)(Ac + (16 + lrow) * 256 + co);
            #pragma unroll
            for (int nf = 0; nf < 2; ++nf) {
                int nfA = w * 2 + nf;
                bf8 b = *(const bf8*)(WcF + ((size_t)(((kc * 8 + nfA) * 4 + t) * 64 + l) << 3));
                acc[0][nf] = MFMA(a0, b, acc[0][nf]);
                acc[1][nf] = MFMA(a1, b, acc[1][nf]);
            }
        }
        __syncthreads();
        cur ^= 1;
    }
    #pragma unroll
    for (int mi = 0; mi < 2; ++mi) {
        #pragma unroll
        for (int nf = 0; nf < 2; ++nf) {
            int nc = w * 32 + nf * 16 + lrow;
            float bias = bc[nc];
            #pragma unroll
            for (int r = 0; r < 4; ++r)
                out[(size_t)(m0 + mi * 16 + lgrp * 4 + r) * D_D + nc] = acc[mi][nf][r] + bias;
        }
    }
}

extern "C" void kernel_launch(void* const* d_in, const int* in_sizes, int n_in,
                              void* d_out, int out_size, void* d_ws, size_t ws_size,
                              hipStream_t stream) {
    const float* query  = (const float*)d_in[0];
    const float* states = (const float*)d_in[1];
    const float* Wk = (const float*)d_in[2];
    const float* bk = (const float*)d_in[3];
    const float* Wv = (const float*)d_in[4];
    const float* bv = (const float*)d_in[5];
    const float* Wc = (const float*)d_in[6];
    const float* bc = (const float*)d_in[7];
    float* out = (float*)d_out;

    // workspace (bf16): Kb 32MB | VTb 32MB | CTX 32MB | WcF 1MB.
    // WkF/WvF (1MB each) OVERLAP the CTX region: consumed by k_proj before
    // k_attn writes CTX -> no extra ws.
    char* ws = (char*)d_ws;
    unsigned short* Kb  = (unsigned short*)(ws);
    unsigned short* VTb = (unsigned short*)(ws + 33554432);
    unsigned short* CTX = (unsigned short*)(ws + 67108864);
    unsigned short* WkF = (unsigned short*)(ws + 67108864);
    unsigned short* WvF = (unsigned short*)(ws + 67108864 + 1048576);
    unsigned short* WcF = (unsigned short*)(ws + 100663296);

    k_wct<<<256, 256, 0, stream>>>(Wc, WcF);
    dim3 gw(32, 2);
    k_wt<<<gw, 256, 0, stream>>>(Wk, Wv, WkF, WvF);
    dim3 gb(2048, 2);
    k_proj<<<gb, 256, 0, stream>>>(states, WkF, bk, WvF, bv, Kb, VTb);
    k_attn<<<512, 512, 0, stream>>>(query, Kb, VTb, CTX);
    k_out<<<128, 256, 0, stream>>>(CTX, WcF, bc, out);
}